// Round 7
// baseline (1852.367 us; speedup 1.0000x reference)
//
#include <hip/hip_runtime.h>

#define N_NODES 50000
#define N_EDGES 800000
#define N_GRAPHS 1000
#define F_IN 128
#define HID 64
#define NBUCK 196          // ceil(N_NODES / 256)
#define BCAP 5120          // per-bucket region capacity (mean 4096)
#define NB   782           // ceil(N_NODES / 64) node-blocks

__device__ __forceinline__ int wave_incl_scan_i(int v, int lane) {
  #pragma unroll
  for (int off = 1; off < 64; off <<= 1) {
    int t = __shfl_up(v, off, 64);
    if (lane >= off) v += t;
  }
  return v;
}

// ---------- CSR build: phase A — bucket edges by dst>>8 ----------
__global__ __launch_bounds__(1024) void k_bucket(const int* __restrict__ src,
                                                 const int* __restrict__ dst,
                                                 int* __restrict__ bucket_cnt,
                                                 int2* __restrict__ region) {
  __shared__ int bcnt[NBUCK];
  __shared__ int lbase[NBUCK];
  __shared__ int gpos[NBUCK];
  __shared__ int2 stage[4096];
  int tid = threadIdx.x;
  if (tid < NBUCK) bcnt[tid] = 0;
  __syncthreads();
  int e0 = blockIdx.x * 4096;
  int2 rec0, rec1, rec2, rec3;
  int bk0 = -1, bk1 = -1, bk2 = -1, bk3 = -1;
  int rk0 = 0, rk1 = 0, rk2 = 0, rk3 = 0;
#define LOADA(i) { int e = e0 + tid + i * 1024;                                  \
    if (e < N_EDGES) { rec##i.x = src[e]; rec##i.y = dst[e];                     \
      bk##i = rec##i.y >> 8; rk##i = atomicAdd(&bcnt[bk##i], 1); } }
  LOADA(0) LOADA(1) LOADA(2) LOADA(3)
#undef LOADA
  __syncthreads();
  if (tid < 64) {   // exclusive scan of bcnt[196]
    int v0 = (tid * 4 + 0 < NBUCK) ? bcnt[tid * 4 + 0] : 0;
    int v1 = (tid * 4 + 1 < NBUCK) ? bcnt[tid * 4 + 1] : 0;
    int v2 = (tid * 4 + 2 < NBUCK) ? bcnt[tid * 4 + 2] : 0;
    int v3 = (tid * 4 + 3 < NBUCK) ? bcnt[tid * 4 + 3] : 0;
    int s = v0 + v1 + v2 + v3;
    int excl = wave_incl_scan_i(s, tid) - s;
    if (tid * 4 + 0 < NBUCK) lbase[tid * 4 + 0] = excl; excl += v0;
    if (tid * 4 + 1 < NBUCK) lbase[tid * 4 + 1] = excl; excl += v1;
    if (tid * 4 + 2 < NBUCK) lbase[tid * 4 + 2] = excl; excl += v2;
    if (tid * 4 + 3 < NBUCK) lbase[tid * 4 + 3] = excl;
  }
  __syncthreads();
  if (tid < NBUCK && bcnt[tid] > 0) gpos[tid] = atomicAdd(&bucket_cnt[tid], bcnt[tid]);
  if (bk0 >= 0) stage[lbase[bk0] + rk0] = rec0;
  if (bk1 >= 0) stage[lbase[bk1] + rk1] = rec1;
  if (bk2 >= 0) stage[lbase[bk2] + rk2] = rec2;
  if (bk3 >= 0) stage[lbase[bk3] + rk3] = rec3;
  __syncthreads();
  int total = lbase[NBUCK - 1] + bcnt[NBUCK - 1];
  for (int j = tid; j < total; j += 1024) {
    int2 r = stage[j];
    int b = r.y >> 8;
    int k = gpos[b] + (j - lbase[b]);
    if (k < BCAP) region[b * BCAP + k] = r;
  }
}

// ---------- CSR build: scan of bucket counts ----------
__global__ void k_bscan(const int* __restrict__ bucket_cnt,
                        int* __restrict__ bucket_base, int* __restrict__ offs) {
  int lane = threadIdx.x;
  int v0 = (lane * 4 + 0 < NBUCK) ? bucket_cnt[lane * 4 + 0] : 0;
  int v1 = (lane * 4 + 1 < NBUCK) ? bucket_cnt[lane * 4 + 1] : 0;
  int v2 = (lane * 4 + 2 < NBUCK) ? bucket_cnt[lane * 4 + 2] : 0;
  int v3 = (lane * 4 + 3 < NBUCK) ? bucket_cnt[lane * 4 + 3] : 0;
  int s = v0 + v1 + v2 + v3;
  int excl = wave_incl_scan_i(s, lane) - s;
  if (lane * 4 + 0 < NBUCK) bucket_base[lane * 4 + 0] = excl; excl += v0;
  if (lane * 4 + 1 < NBUCK) bucket_base[lane * 4 + 1] = excl; excl += v1;
  if (lane * 4 + 2 < NBUCK) bucket_base[lane * 4 + 2] = excl; excl += v2;
  if (lane * 4 + 3 < NBUCK) bucket_base[lane * 4 + 3] = excl;
  if (lane == 0) offs[N_NODES] = N_EDGES;
}

// ---------- CSR build: phase B — per-bucket fine CSR in LDS ----------
// epack[e] = src | (dst_local256 << 16)   (src < 2^16)
__global__ __launch_bounds__(1024) void k_csr(const int2* __restrict__ region,
                                              const int* __restrict__ bucket_cnt,
                                              const int* __restrict__ bucket_base,
                                              int* __restrict__ offs,
                                              float* __restrict__ dis,
                                              int* __restrict__ epack) {
  __shared__ int hist[256];
  __shared__ int base[256];
  __shared__ int stage[BCAP];
  int b = blockIdx.x, tid = threadIdx.x;
  int cnt = bucket_cnt[b]; if (cnt > BCAP) cnt = BCAP;
  int bbase = bucket_base[b];
  if (tid < 256) hist[tid] = 0;
  __syncthreads();
  int rec0, rec1, rec2, rec3, rec4;
  int ln0 = -1, ln1 = -1, ln2 = -1, ln3 = -1, ln4 = -1;
  int rk0 = 0, rk1 = 0, rk2 = 0, rk3 = 0, rk4 = 0;
#define LOADB(i) { int j = tid + i * 1024;                                        \
    if (j < cnt) { int2 r = region[b * BCAP + j]; rec##i = r.x;                   \
      ln##i = r.y & 255; rk##i = atomicAdd(&hist[ln##i], 1); } }
  LOADB(0) LOADB(1) LOADB(2) LOADB(3) LOADB(4)
#undef LOADB
  __syncthreads();
  if (tid < 64) {
    int v0 = hist[tid * 4 + 0], v1 = hist[tid * 4 + 1];
    int v2 = hist[tid * 4 + 2], v3 = hist[tid * 4 + 3];
    int s = v0 + v1 + v2 + v3;
    int excl = wave_incl_scan_i(s, tid) - s;
    base[tid * 4 + 0] = excl; excl += v0;
    base[tid * 4 + 1] = excl; excl += v1;
    base[tid * 4 + 2] = excl; excl += v2;
    base[tid * 4 + 3] = excl;
  }
  __syncthreads();
  int node = b * 256 + tid;
  if (tid < 256 && node < N_NODES) {
    offs[node] = bbase + base[tid];
    dis[node] = rsqrtf(1.0f + (float)hist[tid]);
  }
  if (ln0 >= 0) stage[base[ln0] + rk0] = rec0 | (ln0 << 16);
  if (ln1 >= 0) stage[base[ln1] + rk1] = rec1 | (ln1 << 16);
  if (ln2 >= 0) stage[base[ln2] + rk2] = rec2 | (ln2 << 16);
  if (ln3 >= 0) stage[base[ln3] + rk3] = rec3 | (ln3 << 16);
  if (ln4 >= 0) stage[base[ln4] + rk4] = rec4 | (ln4 << 16);
  __syncthreads();
  for (int j = tid; j < cnt; j += 1024) epack[bbase + j] = stage[j];
}

// ---------- initial GEMM: T[row] = (X[row] @ W) * dis[row], row-major ----------
template<int K>
__global__ __launch_bounds__(256) void k_gemm(const float* __restrict__ X,
                                              const float* __restrict__ W,
                                              const float* __restrict__ dis,
                                              float* __restrict__ T) {
  __shared__ float xs[64 * 64];
  __shared__ float ws[K * 64];
  const int tid = threadIdx.x;
  const int tx = tid & 15, ty = tid >> 4;
  const int row0 = blockIdx.x * 64;

  for (int i = tid; i < K * 16; i += 256)
    *(float4*)&ws[i * 4] = *(const float4*)&W[i * 4];

  float acc[4][4] = {};
  for (int kb = 0; kb < K; kb += 64) {
    __syncthreads();
    for (int i = tid; i < 64 * 16; i += 256) {
      int r = i >> 4, c4 = (i & 15) << 2;
      float4 v = make_float4(0.f, 0.f, 0.f, 0.f);
      int row = row0 + r;
      if (row < N_NODES) v = *(const float4*)&X[row * K + kb + c4];
      *(float4*)&xs[r * 64 + (c4 ^ ((r & 7) << 2))] = v;
    }
    __syncthreads();
    for (int k = 0; k < 64; k += 4) {
      float4 xv[4];
      #pragma unroll
      for (int r = 0; r < 4; ++r) {
        int row = ty * 4 + r;
        xv[r] = *(float4*)&xs[row * 64 + (k ^ ((row & 7) << 2))];
      }
      #pragma unroll
      for (int kk = 0; kk < 4; ++kk) {
        float4 wv = *(float4*)&ws[(kb + k + kk) * 64 + (tx << 2)];
        #pragma unroll
        for (int r = 0; r < 4; ++r) {
          float xr = (kk == 0) ? xv[r].x : (kk == 1) ? xv[r].y
                   : (kk == 2) ? xv[r].z : xv[r].w;
          acc[r][0] = fmaf(xr, wv.x, acc[r][0]);
          acc[r][1] = fmaf(xr, wv.y, acc[r][1]);
          acc[r][2] = fmaf(xr, wv.z, acc[r][2]);
          acc[r][3] = fmaf(xr, wv.w, acc[r][3]);
        }
      }
    }
  }
  #pragma unroll
  for (int r = 0; r < 4; ++r) {
    int row = row0 + ty * 4 + r;
    if (row < N_NODES) {
      float dn = dis[row];
      float4 o = make_float4(acc[r][0] * dn, acc[r][1] * dn,
                             acc[r][2] * dn, acc[r][3] * dn);
      *(float4*)&T[row * 64 + (tx << 2)] = o;
    }
  }
}

// ---------- fused layer: edge-parallel LDS-atomic agg + relu + GEMM ----------
// xs seeded with self-term T[n] (swizzled); edges atomically accumulate;
// epilogue: xs = relu(dis*xs + b); then T' = (xs @ W) * dis, row-major.
__global__ __launch_bounds__(256) void k_layer(const float* __restrict__ T,
                                               const int* __restrict__ offs,
                                               const int* __restrict__ epack,
                                               const float* __restrict__ dis,
                                               const float* __restrict__ bias,
                                               const float* __restrict__ W,
                                               float* __restrict__ Tout) {
  __shared__ float xs[64 * 64];
  __shared__ float ws[64 * 64];
  const int tid = threadIdx.x;
  const int g = blockIdx.x;
  const int n0 = g * 64;

  for (int i = tid; i < 64 * 16; i += 256)
    *(float4*)&ws[i * 4] = *(const float4*)&W[i * 4];

  // seed accumulator with the (pre-scaled) self-loop term, swizzled layout
  for (int idx = tid; idx < 1024; idx += 256) {
    int nloc = idx >> 4, c4 = (idx & 15) << 2;
    int n = n0 + nloc;
    float4 v = make_float4(0.f, 0.f, 0.f, 0.f);
    if (n < N_NODES) v = *(const float4*)&T[n * 64 + c4];
    *(float4*)&xs[nloc * 64 + (c4 ^ ((nloc & 7) << 2))] = v;
  }
  __syncthreads();

  // edge-parallel accumulate: 16 groups of 16 lanes, contiguous chunks
  int hi = n0 + 64; if (hi > N_NODES) hi = N_NODES;
  const int e0 = offs[n0], e1 = offs[hi];
  const int cnt = e1 - e0;
  const int grp = tid >> 4;
  const int f4 = (tid & 15) << 2;
  const int L = (cnt + 15) >> 4;
  int ge0 = e0 + grp * L;
  int ge1 = ge0 + L; if (ge1 > e1) ge1 = e1;
  const int base = (g & 3) << 6;   // node offset within the 256-bucket

#define EDGE1(p) { int s_ = (p) & 0xFFFF; int l_ = ((p) >> 16) - base;           \
    float4 v_ = *(const float4*)&T[s_ * 64 + f4];                                \
    int a_ = l_ * 64 + (f4 ^ ((l_ & 7) << 2));                                   \
    atomicAdd(&xs[a_ + 0], v_.x); atomicAdd(&xs[a_ + 1], v_.y);                  \
    atomicAdd(&xs[a_ + 2], v_.z); atomicAdd(&xs[a_ + 3], v_.w); }
  int e = ge0;
  for (; e + 4 <= ge1; e += 4) {
    int p0 = epack[e], p1 = epack[e + 1], p2 = epack[e + 2], p3 = epack[e + 3];
    EDGE1(p0) EDGE1(p1) EDGE1(p2) EDGE1(p3)
  }
  for (; e < ge1; ++e) { int p = epack[e]; EDGE1(p) }
#undef EDGE1
  __syncthreads();

  // epilogue: relu(dis * acc + bias), in place (same-cell RMW, no race)
  for (int idx = tid; idx < 1024; idx += 256) {
    int nloc = idx >> 4, c4 = (idx & 15) << 2;
    int n = n0 + nloc;
    if (n < N_NODES) {
      float dn = dis[n];
      int a = nloc * 64 + (c4 ^ ((nloc & 7) << 2));
      float4 v = *(float4*)&xs[a];
      float4 bv = *(const float4*)&bias[c4];
      v.x = fmaxf(fmaf(dn, v.x, bv.x), 0.f);
      v.y = fmaxf(fmaf(dn, v.y, bv.y), 0.f);
      v.z = fmaxf(fmaf(dn, v.z, bv.z), 0.f);
      v.w = fmaxf(fmaf(dn, v.w, bv.w), 0.f);
      *(float4*)&xs[a] = v;
    }
  }
  __syncthreads();

  // GEMM: T'[row] = (xs[row] @ W) * dis[row]
  const int tx = tid & 15, ty = tid >> 4;
  float a4[4][4] = {};
  for (int k = 0; k < 64; k += 4) {
    float4 xv[4];
    #pragma unroll
    for (int r = 0; r < 4; ++r) {
      int row = ty * 4 + r;
      xv[r] = *(float4*)&xs[row * 64 + (k ^ ((row & 7) << 2))];
    }
    #pragma unroll
    for (int kk = 0; kk < 4; ++kk) {
      float4 wv = *(float4*)&ws[(k + kk) * 64 + (tx << 2)];
      #pragma unroll
      for (int r = 0; r < 4; ++r) {
        float xr = (kk == 0) ? xv[r].x : (kk == 1) ? xv[r].y
                 : (kk == 2) ? xv[r].z : xv[r].w;
        a4[r][0] = fmaf(xr, wv.x, a4[r][0]);
        a4[r][1] = fmaf(xr, wv.y, a4[r][1]);
        a4[r][2] = fmaf(xr, wv.z, a4[r][2]);
        a4[r][3] = fmaf(xr, wv.w, a4[r][3]);
      }
    }
  }
  #pragma unroll
  for (int r = 0; r < 4; ++r) {
    int row = n0 + ty * 4 + r;
    if (row < N_NODES) {
      float d2 = dis[row];
      float4 o = make_float4(a4[r][0] * d2, a4[r][1] * d2,
                             a4[r][2] * d2, a4[r][3] * d2);
      *(float4*)&Tout[row * 64 + (tx << 2)] = o;
    }
  }
}

// ---------- last layer: agg + relu + dot(Wl) -> per-node scalar ----------
__global__ __launch_bounds__(256) void k_last(const float* __restrict__ T,
                                              const int* __restrict__ offs,
                                              const int* __restrict__ epack,
                                              const float* __restrict__ dis,
                                              const float* __restrict__ bias,
                                              const float* __restrict__ Wl,
                                              float* __restrict__ pern) {
  __shared__ float xs[64 * 64];
  const int tid = threadIdx.x;
  const int g = blockIdx.x;
  const int n0 = g * 64;

  for (int idx = tid; idx < 1024; idx += 256) {
    int nloc = idx >> 4, c4 = (idx & 15) << 2;
    int n = n0 + nloc;
    float4 v = make_float4(0.f, 0.f, 0.f, 0.f);
    if (n < N_NODES) v = *(const float4*)&T[n * 64 + c4];
    *(float4*)&xs[nloc * 64 + (c4 ^ ((nloc & 7) << 2))] = v;
  }
  __syncthreads();

  int hi = n0 + 64; if (hi > N_NODES) hi = N_NODES;
  const int e0 = offs[n0], e1 = offs[hi];
  const int cnt = e1 - e0;
  const int grp = tid >> 4;
  const int f4 = (tid & 15) << 2;
  const int L = (cnt + 15) >> 4;
  int ge0 = e0 + grp * L;
  int ge1 = ge0 + L; if (ge1 > e1) ge1 = e1;
  const int base = (g & 3) << 6;

#define EDGE1(p) { int s_ = (p) & 0xFFFF; int l_ = ((p) >> 16) - base;           \
    float4 v_ = *(const float4*)&T[s_ * 64 + f4];                                \
    int a_ = l_ * 64 + (f4 ^ ((l_ & 7) << 2));                                   \
    atomicAdd(&xs[a_ + 0], v_.x); atomicAdd(&xs[a_ + 1], v_.y);                  \
    atomicAdd(&xs[a_ + 2], v_.z); atomicAdd(&xs[a_ + 3], v_.w); }
  int e = ge0;
  for (; e + 4 <= ge1; e += 4) {
    int p0 = epack[e], p1 = epack[e + 1], p2 = epack[e + 2], p3 = epack[e + 3];
    EDGE1(p0) EDGE1(p1) EDGE1(p2) EDGE1(p3)
  }
  for (; e < ge1; ++e) { int p = epack[e]; EDGE1(p) }
#undef EDGE1
  __syncthreads();

  // epilogue: 4 lanes per node, 16 features each, then shuffle-combine
  int nloc = tid >> 2, q = tid & 3;
  int n = n0 + nloc;
  float sdot = 0.f;
  if (n < N_NODES) {
    float dn = dis[n];
    #pragma unroll
    for (int j = 0; j < 4; ++j) {
      int c4 = q * 16 + j * 4;
      float4 v = *(float4*)&xs[nloc * 64 + (c4 ^ ((nloc & 7) << 2))];
      float4 bv = *(const float4*)&bias[c4];
      float4 wv = *(const float4*)&Wl[c4];
      sdot += fmaxf(fmaf(dn, v.x, bv.x), 0.f) * wv.x
            + fmaxf(fmaf(dn, v.y, bv.y), 0.f) * wv.y
            + fmaxf(fmaf(dn, v.z, bv.z), 0.f) * wv.z
            + fmaxf(fmaf(dn, v.w, bv.w), 0.f) * wv.w;
    }
  }
  sdot += __shfl_xor(sdot, 1, 64);
  sdot += __shfl_xor(sdot, 2, 64);
  if (q == 0 && n < N_NODES) pern[n] = sdot;
}

// ---------- per-graph mean of per-node scalars + bl ----------
__global__ __launch_bounds__(64) void k_pool2(const float* __restrict__ pern,
                                              const int* __restrict__ batch,
                                              const float* __restrict__ bl,
                                              float* __restrict__ out) {
  int g = blockIdx.x;
  int lane = threadIdx.x;
  int lo = 0, hi = N_NODES;
  while (lo < hi) { int mid = (lo + hi) >> 1; if (batch[mid] < g) lo = mid + 1; else hi = mid; }
  int start = lo;
  hi = N_NODES;
  while (lo < hi) { int mid = (lo + hi) >> 1; if (batch[mid] < g + 1) lo = mid + 1; else hi = mid; }
  int end = lo;
  float acc = 0.f;
  for (int nn = start + lane; nn < end; nn += 64) acc += pern[nn];
  #pragma unroll
  for (int off = 32; off; off >>= 1) acc += __shfl_down(acc, off, 64);
  if (lane == 0) {
    float cntf = (float)(end - start);
    out[g] = acc / fmaxf(cntf, 1.0f) + bl[0];
  }
}

extern "C" void kernel_launch(void* const* d_in, const int* in_sizes, int n_in,
                              void* d_out, int out_size, void* d_ws, size_t ws_size,
                              hipStream_t stream) {
  const float* x    = (const float*)d_in[0];
  const float* W1   = (const float*)d_in[1];
  const float* b1   = (const float*)d_in[2];
  const float* W2   = (const float*)d_in[3];
  const float* b2   = (const float*)d_in[4];
  const float* Wl   = (const float*)d_in[5];
  const float* bl   = (const float*)d_in[6];
  const int*   eidx = (const int*)d_in[7];
  const int*   batch= (const int*)d_in[8];
  const int* e_src = eidx;             // edge_index[0]
  const int* e_dst = eidx + N_EDGES;   // edge_index[1]
  float* out = (float*)d_out;

  char* w = (char*)d_ws;
  size_t o = 0;
  auto alloc = [&](size_t bytes) { void* p = w + o; o += (bytes + 255) & ~(size_t)255; return p; };
  float* dis    = (float*)alloc(N_NODES * 4);
  int*   offs   = (int*)  alloc((N_NODES + 1) * 4);
  int*   epack  = (int*)  alloc((size_t)N_EDGES * 4);
  int*   bcnt   = (int*)  alloc(NBUCK * 4);
  int*   bbase  = (int*)  alloc(NBUCK * 4);
  int2*  region = (int2*) alloc((size_t)NBUCK * BCAP * 8);
  float* bufT   = (float*)alloc((size_t)N_NODES * HID * 4);
  float* bufU   = (float*)alloc((size_t)N_NODES * HID * 4);
  float* pern   = (float*)alloc(N_NODES * 4);

  (void)hipMemsetAsync(bcnt, 0, NBUCK * 4, stream);
  k_bucket<<<(N_EDGES + 4095) / 4096, 1024, 0, stream>>>(e_src, e_dst, bcnt, region);
  k_bscan <<<1, 64, 0, stream>>>(bcnt, bbase, offs);
  k_csr   <<<NBUCK, 1024, 0, stream>>>(region, bcnt, bbase, offs, dis, epack);

  k_gemm<F_IN><<<NB, 256, 0, stream>>>(x, W1, dis, bufT);               // -> T1
  k_layer<<<NB, 256, 0, stream>>>(bufT, offs, epack, dis, b1, W2, bufU); // T1->T2
  k_layer<<<NB, 256, 0, stream>>>(bufU, offs, epack, dis, b2, W2, bufT); // T2->T3
  k_layer<<<NB, 256, 0, stream>>>(bufT, offs, epack, dis, b2, W2, bufU); // T3->T4
  k_layer<<<NB, 256, 0, stream>>>(bufU, offs, epack, dis, b2, W2, bufT); // T4->T5
  k_last <<<NB, 256, 0, stream>>>(bufT, offs, epack, dis, b2, Wl, pern);
  k_pool2<<<N_GRAPHS, 64, 0, stream>>>(pern, batch, bl, out);
}

// Round 8
// 258.069 us; speedup vs baseline: 7.1778x; 7.1778x over previous
//
#include <hip/hip_runtime.h>
#include <hip/hip_fp16.h>

#define N_NODES 50000
#define N_EDGES 800000
#define N_GRAPHS 1000
#define F_IN 128
#define HID 64
#define NBUCK 196          // ceil(N_NODES / 256)
#define BCAP 5120          // per-bucket region capacity (mean 4096)

__device__ __forceinline__ int wave_incl_scan_i(int v, int lane) {
  #pragma unroll
  for (int off = 1; off < 64; off <<= 1) {
    int t = __shfl_up(v, off, 64);
    if (lane >= off) v += t;
  }
  return v;
}

// ---------- CSR build: phase A — bucket edges by dst>>8 ----------
__global__ __launch_bounds__(1024) void k_bucket(const int* __restrict__ src,
                                                 const int* __restrict__ dst,
                                                 int* __restrict__ bucket_cnt,
                                                 int2* __restrict__ region) {
  __shared__ int bcnt[NBUCK];
  __shared__ int lbase[NBUCK];
  __shared__ int gpos[NBUCK];
  __shared__ int2 stage[4096];
  int tid = threadIdx.x;
  if (tid < NBUCK) bcnt[tid] = 0;
  __syncthreads();
  int e0 = blockIdx.x * 4096;
  int2 rec0, rec1, rec2, rec3;
  int bk0 = -1, bk1 = -1, bk2 = -1, bk3 = -1;
  int rk0 = 0, rk1 = 0, rk2 = 0, rk3 = 0;
#define LOADA(i) { int e = e0 + tid + i * 1024;                                  \
    if (e < N_EDGES) { rec##i.x = src[e]; rec##i.y = dst[e];                     \
      bk##i = rec##i.y >> 8; rk##i = atomicAdd(&bcnt[bk##i], 1); } }
  LOADA(0) LOADA(1) LOADA(2) LOADA(3)
#undef LOADA
  __syncthreads();
  if (tid < 64) {   // exclusive scan of bcnt[196]
    int v0 = (tid * 4 + 0 < NBUCK) ? bcnt[tid * 4 + 0] : 0;
    int v1 = (tid * 4 + 1 < NBUCK) ? bcnt[tid * 4 + 1] : 0;
    int v2 = (tid * 4 + 2 < NBUCK) ? bcnt[tid * 4 + 2] : 0;
    int v3 = (tid * 4 + 3 < NBUCK) ? bcnt[tid * 4 + 3] : 0;
    int s = v0 + v1 + v2 + v3;
    int excl = wave_incl_scan_i(s, tid) - s;
    if (tid * 4 + 0 < NBUCK) lbase[tid * 4 + 0] = excl; excl += v0;
    if (tid * 4 + 1 < NBUCK) lbase[tid * 4 + 1] = excl; excl += v1;
    if (tid * 4 + 2 < NBUCK) lbase[tid * 4 + 2] = excl; excl += v2;
    if (tid * 4 + 3 < NBUCK) lbase[tid * 4 + 3] = excl;
  }
  __syncthreads();
  if (tid < NBUCK && bcnt[tid] > 0) gpos[tid] = atomicAdd(&bucket_cnt[tid], bcnt[tid]);
  if (bk0 >= 0) stage[lbase[bk0] + rk0] = rec0;
  if (bk1 >= 0) stage[lbase[bk1] + rk1] = rec1;
  if (bk2 >= 0) stage[lbase[bk2] + rk2] = rec2;
  if (bk3 >= 0) stage[lbase[bk3] + rk3] = rec3;
  __syncthreads();
  int total = lbase[NBUCK - 1] + bcnt[NBUCK - 1];
  for (int j = tid; j < total; j += 1024) {
    int2 r = stage[j];
    int b = r.y >> 8;
    int k = gpos[b] + (j - lbase[b]);
    if (k < BCAP) region[b * BCAP + k] = r;
  }
}

// ---------- CSR build: scan of bucket counts ----------
__global__ void k_bscan(const int* __restrict__ bucket_cnt,
                        int* __restrict__ bucket_base, int* __restrict__ offs) {
  int lane = threadIdx.x;
  int v0 = (lane * 4 + 0 < NBUCK) ? bucket_cnt[lane * 4 + 0] : 0;
  int v1 = (lane * 4 + 1 < NBUCK) ? bucket_cnt[lane * 4 + 1] : 0;
  int v2 = (lane * 4 + 2 < NBUCK) ? bucket_cnt[lane * 4 + 2] : 0;
  int v3 = (lane * 4 + 3 < NBUCK) ? bucket_cnt[lane * 4 + 3] : 0;
  int s = v0 + v1 + v2 + v3;
  int excl = wave_incl_scan_i(s, lane) - s;
  if (lane * 4 + 0 < NBUCK) bucket_base[lane * 4 + 0] = excl; excl += v0;
  if (lane * 4 + 1 < NBUCK) bucket_base[lane * 4 + 1] = excl; excl += v1;
  if (lane * 4 + 2 < NBUCK) bucket_base[lane * 4 + 2] = excl; excl += v2;
  if (lane * 4 + 3 < NBUCK) bucket_base[lane * 4 + 3] = excl;
  if (lane == 0) offs[N_NODES] = N_EDGES;
}

// ---------- CSR build: phase B — per-bucket fine CSR in LDS ----------
__global__ __launch_bounds__(1024) void k_csr(const int2* __restrict__ region,
                                              const int* __restrict__ bucket_cnt,
                                              const int* __restrict__ bucket_base,
                                              int* __restrict__ offs,
                                              float* __restrict__ dis,
                                              int* __restrict__ esrc) {
  __shared__ int hist[256];
  __shared__ int base[256];
  __shared__ int stage[BCAP];
  int b = blockIdx.x, tid = threadIdx.x;
  int cnt = bucket_cnt[b]; if (cnt > BCAP) cnt = BCAP;
  int bbase = bucket_base[b];
  if (tid < 256) hist[tid] = 0;
  __syncthreads();
  int rec0, rec1, rec2, rec3, rec4;
  int ln0 = -1, ln1 = -1, ln2 = -1, ln3 = -1, ln4 = -1;
  int rk0 = 0, rk1 = 0, rk2 = 0, rk3 = 0, rk4 = 0;
#define LOADB(i) { int j = tid + i * 1024;                                        \
    if (j < cnt) { int2 r = region[b * BCAP + j]; rec##i = r.x;                   \
      ln##i = r.y & 255; rk##i = atomicAdd(&hist[ln##i], 1); } }
  LOADB(0) LOADB(1) LOADB(2) LOADB(3) LOADB(4)
#undef LOADB
  __syncthreads();
  if (tid < 64) {
    int v0 = hist[tid * 4 + 0], v1 = hist[tid * 4 + 1];
    int v2 = hist[tid * 4 + 2], v3 = hist[tid * 4 + 3];
    int s = v0 + v1 + v2 + v3;
    int excl = wave_incl_scan_i(s, tid) - s;
    base[tid * 4 + 0] = excl; excl += v0;
    base[tid * 4 + 1] = excl; excl += v1;
    base[tid * 4 + 2] = excl; excl += v2;
    base[tid * 4 + 3] = excl;
  }
  __syncthreads();
  int node = b * 256 + tid;
  if (tid < 256 && node < N_NODES) {
    offs[node] = bbase + base[tid];
    dis[node] = rsqrtf(1.0f + (float)hist[tid]);
  }
  if (ln0 >= 0) stage[base[ln0] + rk0] = rec0;
  if (ln1 >= 0) stage[base[ln1] + rk1] = rec1;
  if (ln2 >= 0) stage[base[ln2] + rk2] = rec2;
  if (ln3 >= 0) stage[base[ln3] + rk3] = rec3;
  if (ln4 >= 0) stage[base[ln4] + rk4] = rec4;
  __syncthreads();
  for (int j = tid; j < cnt; j += 1024) esrc[bbase + j] = stage[j];
}

// ---------- fp16 helpers ----------
__device__ __forceinline__ void acc8_fp16(float* acc, uint4 u) {
  float2 f;
  f = __half22float2(*(__half2*)&u.x); acc[0] += f.x; acc[1] += f.y;
  f = __half22float2(*(__half2*)&u.y); acc[2] += f.x; acc[3] += f.y;
  f = __half22float2(*(__half2*)&u.z); acc[4] += f.x; acc[5] += f.y;
  f = __half22float2(*(__half2*)&u.w); acc[6] += f.x; acc[7] += f.y;
}

// ---------- GEMM: T[row][0:64] = fp16( (X[row][:] @ W) * dis[row] ) ----------
template<int K>
__global__ __launch_bounds__(256) void k_gemm(const float* __restrict__ X,
                                              const float* __restrict__ W,
                                              const float* __restrict__ dis,
                                              __half* __restrict__ T) {
  __shared__ float xs[64 * 64];
  __shared__ float ws[K * 64];
  const int tid = threadIdx.x;
  const int tx = tid & 15, ty = tid >> 4;
  const int row0 = blockIdx.x * 64;

  for (int i = tid; i < K * 16; i += 256)
    *(float4*)&ws[i * 4] = *(const float4*)&W[i * 4];

  float acc[4][4] = {};
  for (int kb = 0; kb < K; kb += 64) {
    __syncthreads();
    for (int i = tid; i < 64 * 16; i += 256) {
      int r = i >> 4, c4 = (i & 15) << 2;
      float4 v = make_float4(0.f, 0.f, 0.f, 0.f);
      int row = row0 + r;
      if (row < N_NODES) v = *(const float4*)&X[row * K + kb + c4];
      *(float4*)&xs[r * 64 + (c4 ^ ((r & 7) << 2))] = v;
    }
    __syncthreads();
    for (int k = 0; k < 64; k += 4) {
      float4 xv[4];
      #pragma unroll
      for (int r = 0; r < 4; ++r) {
        int row = ty * 4 + r;
        xv[r] = *(float4*)&xs[row * 64 + (k ^ ((row & 7) << 2))];
      }
      #pragma unroll
      for (int kk = 0; kk < 4; ++kk) {
        float4 wv = *(float4*)&ws[(kb + k + kk) * 64 + (tx << 2)];
        #pragma unroll
        for (int r = 0; r < 4; ++r) {
          float xr = (kk == 0) ? xv[r].x : (kk == 1) ? xv[r].y
                   : (kk == 2) ? xv[r].z : xv[r].w;
          acc[r][0] = fmaf(xr, wv.x, acc[r][0]);
          acc[r][1] = fmaf(xr, wv.y, acc[r][1]);
          acc[r][2] = fmaf(xr, wv.z, acc[r][2]);
          acc[r][3] = fmaf(xr, wv.w, acc[r][3]);
        }
      }
    }
  }
  #pragma unroll
  for (int r = 0; r < 4; ++r) {
    int row = row0 + ty * 4 + r;
    if (row < N_NODES) {
      float dn = dis[row];
      __half2 h0 = __floats2half2_rn(acc[r][0] * dn, acc[r][1] * dn);
      __half2 h1 = __floats2half2_rn(acc[r][2] * dn, acc[r][3] * dn);
      uint2 u = make_uint2(*(unsigned*)&h0, *(unsigned*)&h1);
      *(uint2*)&T[row * 64 + (tx << 2)] = u;
    }
  }
}

// ---------- gather: H[n] = relu(dis[n]*(T[n]+sum T[src])+b), fp16 rows ----------
// 8 lanes per node, each lane owns 8 features (one uint4 = 8 halves per row).
__global__ __launch_bounds__(256) void k_gather(const __half* __restrict__ T,
                                                const int* __restrict__ offs,
                                                const int* __restrict__ esrc,
                                                const float* __restrict__ dis,
                                                const float* __restrict__ bias,
                                                float* __restrict__ H) {
  int tid = threadIdx.x;
  int n = blockIdx.x * 32 + (tid >> 3);
  int l8 = (tid & 7) << 3;                 // feature offset: 8 halves
  if (n >= N_NODES) return;
  int e0 = offs[n], e1 = offs[n + 1];
  float acc[8] = {};
  acc8_fp16(acc, *(const uint4*)&T[n * 64 + l8]);   // self-loop (pre-scaled)
  int e = e0;
  for (; e + 8 <= e1; e += 8) {
    int s0 = esrc[e+0], s1 = esrc[e+1], s2 = esrc[e+2], s3 = esrc[e+3];
    int s4 = esrc[e+4], s5 = esrc[e+5], s6 = esrc[e+6], s7 = esrc[e+7];
    uint4 u0 = *(const uint4*)&T[s0 * 64 + l8];
    uint4 u1 = *(const uint4*)&T[s1 * 64 + l8];
    uint4 u2 = *(const uint4*)&T[s2 * 64 + l8];
    uint4 u3 = *(const uint4*)&T[s3 * 64 + l8];
    uint4 u4 = *(const uint4*)&T[s4 * 64 + l8];
    uint4 u5 = *(const uint4*)&T[s5 * 64 + l8];
    uint4 u6 = *(const uint4*)&T[s6 * 64 + l8];
    uint4 u7 = *(const uint4*)&T[s7 * 64 + l8];
    acc8_fp16(acc, u0); acc8_fp16(acc, u1); acc8_fp16(acc, u2); acc8_fp16(acc, u3);
    acc8_fp16(acc, u4); acc8_fp16(acc, u5); acc8_fp16(acc, u6); acc8_fp16(acc, u7);
  }
  for (; e + 4 <= e1; e += 4) {
    int s0 = esrc[e+0], s1 = esrc[e+1], s2 = esrc[e+2], s3 = esrc[e+3];
    uint4 u0 = *(const uint4*)&T[s0 * 64 + l8];
    uint4 u1 = *(const uint4*)&T[s1 * 64 + l8];
    uint4 u2 = *(const uint4*)&T[s2 * 64 + l8];
    uint4 u3 = *(const uint4*)&T[s3 * 64 + l8];
    acc8_fp16(acc, u0); acc8_fp16(acc, u1); acc8_fp16(acc, u2); acc8_fp16(acc, u3);
  }
  for (; e < e1; ++e) {
    acc8_fp16(acc, *(const uint4*)&T[esrc[e] * 64 + l8]);
  }
  float dn = dis[n];
  float4 o0, o1;
  float4 b0 = *(const float4*)&bias[l8];
  float4 b1 = *(const float4*)&bias[l8 + 4];
  o0.x = fmaxf(fmaf(dn, acc[0], b0.x), 0.f);
  o0.y = fmaxf(fmaf(dn, acc[1], b0.y), 0.f);
  o0.z = fmaxf(fmaf(dn, acc[2], b0.z), 0.f);
  o0.w = fmaxf(fmaf(dn, acc[3], b0.w), 0.f);
  o1.x = fmaxf(fmaf(dn, acc[4], b1.x), 0.f);
  o1.y = fmaxf(fmaf(dn, acc[5], b1.y), 0.f);
  o1.z = fmaxf(fmaf(dn, acc[6], b1.z), 0.f);
  o1.w = fmaxf(fmaf(dn, acc[7], b1.w), 0.f);
  *(float4*)&H[n * 64 + l8] = o0;
  *(float4*)&H[n * 64 + l8 + 4] = o1;
}

// ---------- final: gather + relu + dot(Wl) -> per-node scalar ----------
__global__ __launch_bounds__(256) void k_final(const __half* __restrict__ T,
                                               const int* __restrict__ offs,
                                               const int* __restrict__ esrc,
                                               const float* __restrict__ dis,
                                               const float* __restrict__ bias,
                                               const float* __restrict__ Wl,
                                               float* __restrict__ pern) {
  int tid = threadIdx.x;
  int n = blockIdx.x * 32 + (tid >> 3);
  int l8 = (tid & 7) << 3;
  if (n >= N_NODES) return;
  int e0 = offs[n], e1 = offs[n + 1];
  float acc[8] = {};
  acc8_fp16(acc, *(const uint4*)&T[n * 64 + l8]);
  int e = e0;
  for (; e + 8 <= e1; e += 8) {
    int s0 = esrc[e+0], s1 = esrc[e+1], s2 = esrc[e+2], s3 = esrc[e+3];
    int s4 = esrc[e+4], s5 = esrc[e+5], s6 = esrc[e+6], s7 = esrc[e+7];
    uint4 u0 = *(const uint4*)&T[s0 * 64 + l8];
    uint4 u1 = *(const uint4*)&T[s1 * 64 + l8];
    uint4 u2 = *(const uint4*)&T[s2 * 64 + l8];
    uint4 u3 = *(const uint4*)&T[s3 * 64 + l8];
    uint4 u4 = *(const uint4*)&T[s4 * 64 + l8];
    uint4 u5 = *(const uint4*)&T[s5 * 64 + l8];
    uint4 u6 = *(const uint4*)&T[s6 * 64 + l8];
    uint4 u7 = *(const uint4*)&T[s7 * 64 + l8];
    acc8_fp16(acc, u0); acc8_fp16(acc, u1); acc8_fp16(acc, u2); acc8_fp16(acc, u3);
    acc8_fp16(acc, u4); acc8_fp16(acc, u5); acc8_fp16(acc, u6); acc8_fp16(acc, u7);
  }
  for (; e + 4 <= e1; e += 4) {
    int s0 = esrc[e+0], s1 = esrc[e+1], s2 = esrc[e+2], s3 = esrc[e+3];
    uint4 u0 = *(const uint4*)&T[s0 * 64 + l8];
    uint4 u1 = *(const uint4*)&T[s1 * 64 + l8];
    uint4 u2 = *(const uint4*)&T[s2 * 64 + l8];
    uint4 u3 = *(const uint4*)&T[s3 * 64 + l8];
    acc8_fp16(acc, u0); acc8_fp16(acc, u1); acc8_fp16(acc, u2); acc8_fp16(acc, u3);
  }
  for (; e < e1; ++e) {
    acc8_fp16(acc, *(const uint4*)&T[esrc[e] * 64 + l8]);
  }
  float dn = dis[n];
  float4 b0 = *(const float4*)&bias[l8];
  float4 b1 = *(const float4*)&bias[l8 + 4];
  float4 w0 = *(const float4*)&Wl[l8];
  float4 w1 = *(const float4*)&Wl[l8 + 4];
  float s = fmaxf(fmaf(dn, acc[0], b0.x), 0.f) * w0.x
          + fmaxf(fmaf(dn, acc[1], b0.y), 0.f) * w0.y
          + fmaxf(fmaf(dn, acc[2], b0.z), 0.f) * w0.z
          + fmaxf(fmaf(dn, acc[3], b0.w), 0.f) * w0.w
          + fmaxf(fmaf(dn, acc[4], b1.x), 0.f) * w1.x
          + fmaxf(fmaf(dn, acc[5], b1.y), 0.f) * w1.y
          + fmaxf(fmaf(dn, acc[6], b1.z), 0.f) * w1.z
          + fmaxf(fmaf(dn, acc[7], b1.w), 0.f) * w1.w;
  s += __shfl_xor(s, 1, 64);
  s += __shfl_xor(s, 2, 64);
  s += __shfl_xor(s, 4, 64);
  if ((tid & 7) == 0) pern[n] = s;
}

// ---------- per-graph mean of per-node scalars + bl ----------
__global__ __launch_bounds__(64) void k_pool2(const float* __restrict__ pern,
                                              const int* __restrict__ batch,
                                              const float* __restrict__ bl,
                                              float* __restrict__ out) {
  int g = blockIdx.x;
  int lane = threadIdx.x;
  int lo = 0, hi = N_NODES;
  while (lo < hi) { int mid = (lo + hi) >> 1; if (batch[mid] < g) lo = mid + 1; else hi = mid; }
  int start = lo;
  hi = N_NODES;
  while (lo < hi) { int mid = (lo + hi) >> 1; if (batch[mid] < g + 1) lo = mid + 1; else hi = mid; }
  int end = lo;
  float acc = 0.f;
  for (int nn = start + lane; nn < end; nn += 64) acc += pern[nn];
  #pragma unroll
  for (int off = 32; off; off >>= 1) acc += __shfl_down(acc, off, 64);
  if (lane == 0) {
    float cntf = (float)(end - start);
    out[g] = acc / fmaxf(cntf, 1.0f) + bl[0];
  }
}

extern "C" void kernel_launch(void* const* d_in, const int* in_sizes, int n_in,
                              void* d_out, int out_size, void* d_ws, size_t ws_size,
                              hipStream_t stream) {
  const float* x    = (const float*)d_in[0];
  const float* W1   = (const float*)d_in[1];
  const float* b1   = (const float*)d_in[2];
  const float* W2   = (const float*)d_in[3];
  const float* b2   = (const float*)d_in[4];
  const float* Wl   = (const float*)d_in[5];
  const float* bl   = (const float*)d_in[6];
  const int*   eidx = (const int*)d_in[7];
  const int*   batch= (const int*)d_in[8];
  const int* e_src = eidx;             // edge_index[0]
  const int* e_dst = eidx + N_EDGES;   // edge_index[1]
  float* out = (float*)d_out;

  char* w = (char*)d_ws;
  size_t o = 0;
  auto alloc = [&](size_t bytes) { void* p = w + o; o += (bytes + 255) & ~(size_t)255; return p; };
  float*  dis    = (float*) alloc(N_NODES * 4);
  int*    offs   = (int*)   alloc((N_NODES + 1) * 4);
  int*    esrc   = (int*)   alloc((size_t)N_EDGES * 4);
  int*    bcnt   = (int*)   alloc(NBUCK * 4);
  int*    bbase  = (int*)   alloc(NBUCK * 4);
  int2*   region = (int2*)  alloc((size_t)NBUCK * BCAP * 8);
  __half* bufT   = (__half*)alloc((size_t)N_NODES * HID * 2);
  float*  bufH   = (float*) alloc((size_t)N_NODES * HID * 4);
  float*  pern   = (float*) alloc(N_NODES * 4);

  const int NBG = (N_NODES + 63) / 64;   // GEMM blocks (64 rows)
  const int NGA = (N_NODES + 31) / 32;   // gather blocks (32 nodes)

  (void)hipMemsetAsync(bcnt, 0, NBUCK * 4, stream);
  k_bucket<<<(N_EDGES + 4095) / 4096, 1024, 0, stream>>>(e_src, e_dst, bcnt, region);
  k_bscan <<<1, 64, 0, stream>>>(bcnt, bbase, offs);
  k_csr   <<<NBUCK, 1024, 0, stream>>>(region, bcnt, bbase, offs, dis, esrc);

  k_gemm<F_IN><<<NBG, 256, 0, stream>>>(x, W1, dis, bufT);
  k_gather    <<<NGA, 256, 0, stream>>>(bufT, offs, esrc, dis, b1, bufH);
  for (int l = 0; l < 3; ++l) {
    k_gemm<HID><<<NBG, 256, 0, stream>>>(bufH, W2, dis, bufT);
    k_gather   <<<NGA, 256, 0, stream>>>(bufT, offs, esrc, dis, b2, bufH);
  }
  k_gemm<HID> <<<NBG, 256, 0, stream>>>(bufH, W2, dis, bufT);
  k_final     <<<NGA, 256, 0, stream>>>(bufT, offs, esrc, dis, b2, Wl, pern);
  k_pool2     <<<N_GRAPHS, 64, 0, stream>>>(pern, batch, bl, out);
}

// Round 9
// 176.695 us; speedup vs baseline: 10.4834x; 1.4605x over previous
//
#include <hip/hip_runtime.h>
#include <hip/hip_fp16.h>

#define N_NODES 50000
#define N_EDGES 800000
#define N_GRAPHS 1000
#define F_IN 128
#define HID 64
#define NBUCK 196          // ceil(N_NODES / 256)
#define BCAP 5120          // per-bucket region capacity (mean 4096)

typedef _Float16 half8 __attribute__((ext_vector_type(8)));
typedef float f32x4v __attribute__((ext_vector_type(4)));

__device__ __forceinline__ int wave_incl_scan_i(int v, int lane) {
  #pragma unroll
  for (int off = 1; off < 64; off <<= 1) {
    int t = __shfl_up(v, off, 64);
    if (lane >= off) v += t;
  }
  return v;
}

// ---------- CSR build: phase A — bucket edges by dst>>8 ----------
__global__ __launch_bounds__(1024) void k_bucket(const int* __restrict__ src,
                                                 const int* __restrict__ dst,
                                                 int* __restrict__ bucket_cnt,
                                                 int2* __restrict__ region) {
  __shared__ int bcnt[NBUCK];
  __shared__ int lbase[NBUCK];
  __shared__ int gpos[NBUCK];
  __shared__ int2 stage[4096];
  int tid = threadIdx.x;
  if (tid < NBUCK) bcnt[tid] = 0;
  __syncthreads();
  int e0 = blockIdx.x * 4096;
  int2 rec0, rec1, rec2, rec3;
  int bk0 = -1, bk1 = -1, bk2 = -1, bk3 = -1;
  int rk0 = 0, rk1 = 0, rk2 = 0, rk3 = 0;
#define LOADA(i) { int e = e0 + tid + i * 1024;                                  \
    if (e < N_EDGES) { rec##i.x = src[e]; rec##i.y = dst[e];                     \
      bk##i = rec##i.y >> 8; rk##i = atomicAdd(&bcnt[bk##i], 1); } }
  LOADA(0) LOADA(1) LOADA(2) LOADA(3)
#undef LOADA
  __syncthreads();
  if (tid < 64) {   // exclusive scan of bcnt[196]
    int v0 = (tid * 4 + 0 < NBUCK) ? bcnt[tid * 4 + 0] : 0;
    int v1 = (tid * 4 + 1 < NBUCK) ? bcnt[tid * 4 + 1] : 0;
    int v2 = (tid * 4 + 2 < NBUCK) ? bcnt[tid * 4 + 2] : 0;
    int v3 = (tid * 4 + 3 < NBUCK) ? bcnt[tid * 4 + 3] : 0;
    int s = v0 + v1 + v2 + v3;
    int excl = wave_incl_scan_i(s, tid) - s;
    if (tid * 4 + 0 < NBUCK) lbase[tid * 4 + 0] = excl; excl += v0;
    if (tid * 4 + 1 < NBUCK) lbase[tid * 4 + 1] = excl; excl += v1;
    if (tid * 4 + 2 < NBUCK) lbase[tid * 4 + 2] = excl; excl += v2;
    if (tid * 4 + 3 < NBUCK) lbase[tid * 4 + 3] = excl;
  }
  __syncthreads();
  if (tid < NBUCK && bcnt[tid] > 0) gpos[tid] = atomicAdd(&bucket_cnt[tid], bcnt[tid]);
  if (bk0 >= 0) stage[lbase[bk0] + rk0] = rec0;
  if (bk1 >= 0) stage[lbase[bk1] + rk1] = rec1;
  if (bk2 >= 0) stage[lbase[bk2] + rk2] = rec2;
  if (bk3 >= 0) stage[lbase[bk3] + rk3] = rec3;
  __syncthreads();
  int total = lbase[NBUCK - 1] + bcnt[NBUCK - 1];
  for (int j = tid; j < total; j += 1024) {
    int2 r = stage[j];
    int b = r.y >> 8;
    int k = gpos[b] + (j - lbase[b]);
    if (k < BCAP) region[b * BCAP + k] = r;
  }
}

// ---------- CSR build: scan of bucket counts ----------
__global__ void k_bscan(const int* __restrict__ bucket_cnt,
                        int* __restrict__ bucket_base, int* __restrict__ offs) {
  int lane = threadIdx.x;
  int v0 = (lane * 4 + 0 < NBUCK) ? bucket_cnt[lane * 4 + 0] : 0;
  int v1 = (lane * 4 + 1 < NBUCK) ? bucket_cnt[lane * 4 + 1] : 0;
  int v2 = (lane * 4 + 2 < NBUCK) ? bucket_cnt[lane * 4 + 2] : 0;
  int v3 = (lane * 4 + 3 < NBUCK) ? bucket_cnt[lane * 4 + 3] : 0;
  int s = v0 + v1 + v2 + v3;
  int excl = wave_incl_scan_i(s, lane) - s;
  if (lane * 4 + 0 < NBUCK) bucket_base[lane * 4 + 0] = excl; excl += v0;
  if (lane * 4 + 1 < NBUCK) bucket_base[lane * 4 + 1] = excl; excl += v1;
  if (lane * 4 + 2 < NBUCK) bucket_base[lane * 4 + 2] = excl; excl += v2;
  if (lane * 4 + 3 < NBUCK) bucket_base[lane * 4 + 3] = excl;
  if (lane == 0) offs[N_NODES] = N_EDGES;
}

// ---------- CSR build: phase B — per-bucket fine CSR in LDS ----------
__global__ __launch_bounds__(1024) void k_csr(const int2* __restrict__ region,
                                              const int* __restrict__ bucket_cnt,
                                              const int* __restrict__ bucket_base,
                                              int* __restrict__ offs,
                                              float* __restrict__ dis,
                                              int* __restrict__ esrc) {
  __shared__ int hist[256];
  __shared__ int base[256];
  __shared__ int stage[BCAP];
  int b = blockIdx.x, tid = threadIdx.x;
  int cnt = bucket_cnt[b]; if (cnt > BCAP) cnt = BCAP;
  int bbase = bucket_base[b];
  if (tid < 256) hist[tid] = 0;
  __syncthreads();
  int rec0, rec1, rec2, rec3, rec4;
  int ln0 = -1, ln1 = -1, ln2 = -1, ln3 = -1, ln4 = -1;
  int rk0 = 0, rk1 = 0, rk2 = 0, rk3 = 0, rk4 = 0;
#define LOADB(i) { int j = tid + i * 1024;                                        \
    if (j < cnt) { int2 r = region[b * BCAP + j]; rec##i = r.x;                   \
      ln##i = r.y & 255; rk##i = atomicAdd(&hist[ln##i], 1); } }
  LOADB(0) LOADB(1) LOADB(2) LOADB(3) LOADB(4)
#undef LOADB
  __syncthreads();
  if (tid < 64) {
    int v0 = hist[tid * 4 + 0], v1 = hist[tid * 4 + 1];
    int v2 = hist[tid * 4 + 2], v3 = hist[tid * 4 + 3];
    int s = v0 + v1 + v2 + v3;
    int excl = wave_incl_scan_i(s, tid) - s;
    base[tid * 4 + 0] = excl; excl += v0;
    base[tid * 4 + 1] = excl; excl += v1;
    base[tid * 4 + 2] = excl; excl += v2;
    base[tid * 4 + 3] = excl;
  }
  __syncthreads();
  int node = b * 256 + tid;
  if (tid < 256 && node < N_NODES) {
    offs[node] = bbase + base[tid];
    dis[node] = rsqrtf(1.0f + (float)hist[tid]);
  }
  if (ln0 >= 0) stage[base[ln0] + rk0] = rec0;
  if (ln1 >= 0) stage[base[ln1] + rk1] = rec1;
  if (ln2 >= 0) stage[base[ln2] + rk2] = rec2;
  if (ln3 >= 0) stage[base[ln3] + rk3] = rec3;
  if (ln4 >= 0) stage[base[ln4] + rk4] = rec4;
  __syncthreads();
  for (int j = tid; j < cnt; j += 1024) esrc[bbase + j] = stage[j];
}

// ---------- fp16 helpers ----------
__device__ __forceinline__ void acc8_fp16(float* acc, uint4 u) {
  float2 f;
  f = __half22float2(*(__half2*)&u.x); acc[0] += f.x; acc[1] += f.y;
  f = __half22float2(*(__half2*)&u.y); acc[2] += f.x; acc[3] += f.y;
  f = __half22float2(*(__half2*)&u.z); acc[4] += f.x; acc[5] += f.y;
  f = __half22float2(*(__half2*)&u.w); acc[6] += f.x; acc[7] += f.y;
}

// ---------- layer-1 GEMM (fp32 X input): T = fp16((X @ W) * dis) ----------
template<int K>
__global__ __launch_bounds__(256) void k_gemm(const float* __restrict__ X,
                                              const float* __restrict__ W,
                                              const float* __restrict__ dis,
                                              __half* __restrict__ T) {
  __shared__ float xs[64 * 64];
  __shared__ float ws[K * 64];
  const int tid = threadIdx.x;
  const int tx = tid & 15, ty = tid >> 4;
  const int row0 = blockIdx.x * 64;

  for (int i = tid; i < K * 16; i += 256)
    *(float4*)&ws[i * 4] = *(const float4*)&W[i * 4];

  float acc[4][4] = {};
  for (int kb = 0; kb < K; kb += 64) {
    __syncthreads();
    for (int i = tid; i < 64 * 16; i += 256) {
      int r = i >> 4, c4 = (i & 15) << 2;
      float4 v = make_float4(0.f, 0.f, 0.f, 0.f);
      int row = row0 + r;
      if (row < N_NODES) v = *(const float4*)&X[row * K + kb + c4];
      *(float4*)&xs[r * 64 + (c4 ^ ((r & 7) << 2))] = v;
    }
    __syncthreads();
    for (int k = 0; k < 64; k += 4) {
      float4 xv[4];
      #pragma unroll
      for (int r = 0; r < 4; ++r) {
        int row = ty * 4 + r;
        xv[r] = *(float4*)&xs[row * 64 + (k ^ ((row & 7) << 2))];
      }
      #pragma unroll
      for (int kk = 0; kk < 4; ++kk) {
        float4 wv = *(float4*)&ws[(kb + k + kk) * 64 + (tx << 2)];
        #pragma unroll
        for (int r = 0; r < 4; ++r) {
          float xr = (kk == 0) ? xv[r].x : (kk == 1) ? xv[r].y
                   : (kk == 2) ? xv[r].z : xv[r].w;
          acc[r][0] = fmaf(xr, wv.x, acc[r][0]);
          acc[r][1] = fmaf(xr, wv.y, acc[r][1]);
          acc[r][2] = fmaf(xr, wv.z, acc[r][2]);
          acc[r][3] = fmaf(xr, wv.w, acc[r][3]);
        }
      }
    }
  }
  #pragma unroll
  for (int r = 0; r < 4; ++r) {
    int row = row0 + ty * 4 + r;
    if (row < N_NODES) {
      float dn = dis[row];
      __half2 h0 = __floats2half2_rn(acc[r][0] * dn, acc[r][1] * dn);
      __half2 h1 = __floats2half2_rn(acc[r][2] * dn, acc[r][3] * dn);
      uint2 u = make_uint2(*(unsigned*)&h0, *(unsigned*)&h1);
      *(uint2*)&T[row * 64 + (tx << 2)] = u;
    }
  }
}

// ---------- inner GEMM via MFMA: T = fp16((H @ W) * dis), H fp16 ----------
// W2 staged transposed + XOR-swizzled fp16 in LDS; A read direct from global H.
// MFMA 16x16x32_f16 layouts: A lane l -> row l&15, k 8*(l>>4)+j;
// B lane l -> col l&15, k 8*(l>>4)+j; C/D lane l,reg r -> row 4*(l>>4)+r, col l&15.
__global__ __launch_bounds__(256) void k_gemm_mfma(const __half* __restrict__ H,
                                                   const float* __restrict__ W,
                                                   const float* __restrict__ dis,
                                                   __half* __restrict__ T) {
  __shared__ __half wt[64 * 64];   // wt[col][k], swizzled: byte ^= (col&7)<<4
  const int tid = threadIdx.x;
  for (int i = tid; i < 4096; i += 256) {
    int k = i >> 6, n = i & 63;
    int boff = (n << 7) + (((k << 1)) ^ ((n & 7) << 4));
    *(__half*)((char*)wt + boff) = __float2half(W[i]);
  }
  __syncthreads();

  const int w = tid >> 6;              // wave id: rows 16w..16w+15
  const int l = tid & 63;
  const int row0 = blockIdx.x * 64 + w * 16;
  const int arow = row0 + (l & 15);
  const int koff = (l >> 4) << 3;      // 0,8,16,24

  half8 a0 = {}, a1 = {};
  if (arow < N_NODES) {
    a0 = *(const half8*)&H[arow * 64 + koff];        // k-step 0: k = koff..+7
    a1 = *(const half8*)&H[arow * 64 + 32 + koff];   // k-step 1
  }
  f32x4v acc[4] = {{0.f,0.f,0.f,0.f},{0.f,0.f,0.f,0.f},
                   {0.f,0.f,0.f,0.f},{0.f,0.f,0.f,0.f}};
  #pragma unroll
  for (int t = 0; t < 4; ++t) {
    int col = (t << 4) + (l & 15);
    half8 b0 = *(const half8*)((const char*)wt +
                ((col << 7) + (((koff) << 1) ^ ((col & 7) << 4))));
    half8 b1 = *(const half8*)((const char*)wt +
                ((col << 7) + (((koff + 32) << 1) ^ ((col & 7) << 4))));
    acc[t] = __builtin_amdgcn_mfma_f32_16x16x32_f16(a0, b0, acc[t], 0, 0, 0);
    acc[t] = __builtin_amdgcn_mfma_f32_16x16x32_f16(a1, b1, acc[t], 0, 0, 0);
  }
  #pragma unroll
  for (int r = 0; r < 4; ++r) {
    int row = row0 + ((l >> 4) << 2) + r;
    if (row < N_NODES) {
      float dn = dis[row];
      #pragma unroll
      for (int t = 0; t < 4; ++t)
        T[row * 64 + (t << 4) + (l & 15)] = __float2half(acc[t][r] * dn);
    }
  }
}

// ---------- gather: H16[n] = fp16(relu(dis[n]*(T[n]+sum T[src])+b)) ----------
// 8 lanes per node, each lane owns 8 features (one uint4 = 8 halves per row).
__global__ __launch_bounds__(256) void k_gather(const __half* __restrict__ T,
                                                const int* __restrict__ offs,
                                                const int* __restrict__ esrc,
                                                const float* __restrict__ dis,
                                                const float* __restrict__ bias,
                                                __half* __restrict__ H) {
  int tid = threadIdx.x;
  int n = blockIdx.x * 32 + (tid >> 3);
  int l8 = (tid & 7) << 3;                 // feature offset: 8 halves
  if (n >= N_NODES) return;
  int e0 = offs[n], e1 = offs[n + 1];
  float acc[8] = {};
  acc8_fp16(acc, *(const uint4*)&T[n * 64 + l8]);   // self-loop (pre-scaled)
  int e = e0;
  for (; e + 8 <= e1; e += 8) {
    int s0 = esrc[e+0], s1 = esrc[e+1], s2 = esrc[e+2], s3 = esrc[e+3];
    int s4 = esrc[e+4], s5 = esrc[e+5], s6 = esrc[e+6], s7 = esrc[e+7];
    uint4 u0 = *(const uint4*)&T[s0 * 64 + l8];
    uint4 u1 = *(const uint4*)&T[s1 * 64 + l8];
    uint4 u2 = *(const uint4*)&T[s2 * 64 + l8];
    uint4 u3 = *(const uint4*)&T[s3 * 64 + l8];
    uint4 u4 = *(const uint4*)&T[s4 * 64 + l8];
    uint4 u5 = *(const uint4*)&T[s5 * 64 + l8];
    uint4 u6 = *(const uint4*)&T[s6 * 64 + l8];
    uint4 u7 = *(const uint4*)&T[s7 * 64 + l8];
    acc8_fp16(acc, u0); acc8_fp16(acc, u1); acc8_fp16(acc, u2); acc8_fp16(acc, u3);
    acc8_fp16(acc, u4); acc8_fp16(acc, u5); acc8_fp16(acc, u6); acc8_fp16(acc, u7);
  }
  for (; e + 4 <= e1; e += 4) {
    int s0 = esrc[e+0], s1 = esrc[e+1], s2 = esrc[e+2], s3 = esrc[e+3];
    uint4 u0 = *(const uint4*)&T[s0 * 64 + l8];
    uint4 u1 = *(const uint4*)&T[s1 * 64 + l8];
    uint4 u2 = *(const uint4*)&T[s2 * 64 + l8];
    uint4 u3 = *(const uint4*)&T[s3 * 64 + l8];
    acc8_fp16(acc, u0); acc8_fp16(acc, u1); acc8_fp16(acc, u2); acc8_fp16(acc, u3);
  }
  for (; e < e1; ++e) {
    acc8_fp16(acc, *(const uint4*)&T[esrc[e] * 64 + l8]);
  }
  float dn = dis[n];
  float4 b0 = *(const float4*)&bias[l8];
  float4 b1 = *(const float4*)&bias[l8 + 4];
  __half2 h0 = __floats2half2_rn(fmaxf(fmaf(dn, acc[0], b0.x), 0.f),
                                 fmaxf(fmaf(dn, acc[1], b0.y), 0.f));
  __half2 h1 = __floats2half2_rn(fmaxf(fmaf(dn, acc[2], b0.z), 0.f),
                                 fmaxf(fmaf(dn, acc[3], b0.w), 0.f));
  __half2 h2 = __floats2half2_rn(fmaxf(fmaf(dn, acc[4], b1.x), 0.f),
                                 fmaxf(fmaf(dn, acc[5], b1.y), 0.f));
  __half2 h3 = __floats2half2_rn(fmaxf(fmaf(dn, acc[6], b1.z), 0.f),
                                 fmaxf(fmaf(dn, acc[7], b1.w), 0.f));
  uint4 u = make_uint4(*(unsigned*)&h0, *(unsigned*)&h1,
                       *(unsigned*)&h2, *(unsigned*)&h3);
  *(uint4*)&H[n * 64 + l8] = u;
}

// ---------- final: gather + relu + dot(Wl) -> per-node scalar ----------
__global__ __launch_bounds__(256) void k_final(const __half* __restrict__ T,
                                               const int* __restrict__ offs,
                                               const int* __restrict__ esrc,
                                               const float* __restrict__ dis,
                                               const float* __restrict__ bias,
                                               const float* __restrict__ Wl,
                                               float* __restrict__ pern) {
  int tid = threadIdx.x;
  int n = blockIdx.x * 32 + (tid >> 3);
  int l8 = (tid & 7) << 3;
  if (n >= N_NODES) return;
  int e0 = offs[n], e1 = offs[n + 1];
  float acc[8] = {};
  acc8_fp16(acc, *(const uint4*)&T[n * 64 + l8]);
  int e = e0;
  for (; e + 8 <= e1; e += 8) {
    int s0 = esrc[e+0], s1 = esrc[e+1], s2 = esrc[e+2], s3 = esrc[e+3];
    int s4 = esrc[e+4], s5 = esrc[e+5], s6 = esrc[e+6], s7 = esrc[e+7];
    uint4 u0 = *(const uint4*)&T[s0 * 64 + l8];
    uint4 u1 = *(const uint4*)&T[s1 * 64 + l8];
    uint4 u2 = *(const uint4*)&T[s2 * 64 + l8];
    uint4 u3 = *(const uint4*)&T[s3 * 64 + l8];
    uint4 u4 = *(const uint4*)&T[s4 * 64 + l8];
    uint4 u5 = *(const uint4*)&T[s5 * 64 + l8];
    uint4 u6 = *(const uint4*)&T[s6 * 64 + l8];
    uint4 u7 = *(const uint4*)&T[s7 * 64 + l8];
    acc8_fp16(acc, u0); acc8_fp16(acc, u1); acc8_fp16(acc, u2); acc8_fp16(acc, u3);
    acc8_fp16(acc, u4); acc8_fp16(acc, u5); acc8_fp16(acc, u6); acc8_fp16(acc, u7);
  }
  for (; e + 4 <= e1; e += 4) {
    int s0 = esrc[e+0], s1 = esrc[e+1], s2 = esrc[e+2], s3 = esrc[e+3];
    uint4 u0 = *(const uint4*)&T[s0 * 64 + l8];
    uint4 u1 = *(const uint4*)&T[s1 * 64 + l8];
    uint4 u2 = *(const uint4*)&T[s2 * 64 + l8];
    uint4 u3 = *(const uint4*)&T[s3 * 64 + l8];
    acc8_fp16(acc, u0); acc8_fp16(acc, u1); acc8_fp16(acc, u2); acc8_fp16(acc, u3);
  }
  for (; e < e1; ++e) {
    acc8_fp16(acc, *(const uint4*)&T[esrc[e] * 64 + l8]);
  }
  float dn = dis[n];
  float4 b0 = *(const float4*)&bias[l8];
  float4 b1 = *(const float4*)&bias[l8 + 4];
  float4 w0 = *(const float4*)&Wl[l8];
  float4 w1 = *(const float4*)&Wl[l8 + 4];
  float s = fmaxf(fmaf(dn, acc[0], b0.x), 0.f) * w0.x
          + fmaxf(fmaf(dn, acc[1], b0.y), 0.f) * w0.y
          + fmaxf(fmaf(dn, acc[2], b0.z), 0.f) * w0.z
          + fmaxf(fmaf(dn, acc[3], b0.w), 0.f) * w0.w
          + fmaxf(fmaf(dn, acc[4], b1.x), 0.f) * w1.x
          + fmaxf(fmaf(dn, acc[5], b1.y), 0.f) * w1.y
          + fmaxf(fmaf(dn, acc[6], b1.z), 0.f) * w1.z
          + fmaxf(fmaf(dn, acc[7], b1.w), 0.f) * w1.w;
  s += __shfl_xor(s, 1, 64);
  s += __shfl_xor(s, 2, 64);
  s += __shfl_xor(s, 4, 64);
  if ((tid & 7) == 0) pern[n] = s;
}

// ---------- per-graph mean of per-node scalars + bl ----------
__global__ __launch_bounds__(64) void k_pool2(const float* __restrict__ pern,
                                              const int* __restrict__ batch,
                                              const float* __restrict__ bl,
                                              float* __restrict__ out) {
  int g = blockIdx.x;
  int lane = threadIdx.x;
  int lo = 0, hi = N_NODES;
  while (lo < hi) { int mid = (lo + hi) >> 1; if (batch[mid] < g) lo = mid + 1; else hi = mid; }
  int start = lo;
  hi = N_NODES;
  while (lo < hi) { int mid = (lo + hi) >> 1; if (batch[mid] < g + 1) lo = mid + 1; else hi = mid; }
  int end = lo;
  float acc = 0.f;
  for (int nn = start + lane; nn < end; nn += 64) acc += pern[nn];
  #pragma unroll
  for (int off = 32; off; off >>= 1) acc += __shfl_down(acc, off, 64);
  if (lane == 0) {
    float cntf = (float)(end - start);
    out[g] = acc / fmaxf(cntf, 1.0f) + bl[0];
  }
}

extern "C" void kernel_launch(void* const* d_in, const int* in_sizes, int n_in,
                              void* d_out, int out_size, void* d_ws, size_t ws_size,
                              hipStream_t stream) {
  const float* x    = (const float*)d_in[0];
  const float* W1   = (const float*)d_in[1];
  const float* b1   = (const float*)d_in[2];
  const float* W2   = (const float*)d_in[3];
  const float* b2   = (const float*)d_in[4];
  const float* Wl   = (const float*)d_in[5];
  const float* bl   = (const float*)d_in[6];
  const int*   eidx = (const int*)d_in[7];
  const int*   batch= (const int*)d_in[8];
  const int* e_src = eidx;             // edge_index[0]
  const int* e_dst = eidx + N_EDGES;   // edge_index[1]
  float* out = (float*)d_out;

  char* w = (char*)d_ws;
  size_t o = 0;
  auto alloc = [&](size_t bytes) { void* p = w + o; o += (bytes + 255) & ~(size_t)255; return p; };
  float*  dis    = (float*) alloc(N_NODES * 4);
  int*    offs   = (int*)   alloc((N_NODES + 1) * 4);
  int*    esrc   = (int*)   alloc((size_t)N_EDGES * 4);
  int*    bcnt   = (int*)   alloc(NBUCK * 4);
  int*    bbase  = (int*)   alloc(NBUCK * 4);
  int2*   region = (int2*)  alloc((size_t)NBUCK * BCAP * 8);
  __half* bufT   = (__half*)alloc((size_t)N_NODES * HID * 2);
  __half* bufH   = (__half*)alloc((size_t)N_NODES * HID * 2);
  float*  pern   = (float*) alloc(N_NODES * 4);

  const int NBG = (N_NODES + 63) / 64;   // GEMM blocks (64 rows)
  const int NGA = (N_NODES + 31) / 32;   // gather blocks (32 nodes)

  (void)hipMemsetAsync(bcnt, 0, NBUCK * 4, stream);
  k_bucket<<<(N_EDGES + 4095) / 4096, 1024, 0, stream>>>(e_src, e_dst, bcnt, region);
  k_bscan <<<1, 64, 0, stream>>>(bcnt, bbase, offs);
  k_csr   <<<NBUCK, 1024, 0, stream>>>(region, bcnt, bbase, offs, dis, esrc);

  k_gemm<F_IN><<<NBG, 256, 0, stream>>>(x, W1, dis, bufT);
  k_gather    <<<NGA, 256, 0, stream>>>(bufT, offs, esrc, dis, b1, bufH);
  for (int l = 0; l < 3; ++l) {
    k_gemm_mfma<<<NBG, 256, 0, stream>>>(bufH, W2, dis, bufT);
    k_gather   <<<NGA, 256, 0, stream>>>(bufT, offs, esrc, dis, b2, bufH);
  }
  k_gemm_mfma <<<NBG, 256, 0, stream>>>(bufH, W2, dis, bufT);
  k_final     <<<NGA, 256, 0, stream>>>(bufT, offs, esrc, dis, b2, Wl, pern);
  k_pool2     <<<N_GRAPHS, 64, 0, stream>>>(pern, batch, bl, out);
}

// Round 10
// 140.939 us; speedup vs baseline: 13.1431x; 1.2537x over previous
//
#include <hip/hip_runtime.h>
#include <hip/hip_fp16.h>

#define N_NODES 50000
#define N_EDGES 800000
#define N_GRAPHS 1000
#define F_IN 128
#define HID 64
#define NBUCK 196          // ceil(N_NODES / 256)
#define BCAP 5120          // per-bucket region capacity (mean 4096)

typedef _Float16 half8 __attribute__((ext_vector_type(8)));
typedef float f32x4v __attribute__((ext_vector_type(4)));

__device__ __forceinline__ int wave_incl_scan_i(int v, int lane) {
  #pragma unroll
  for (int off = 1; off < 64; off <<= 1) {
    int t = __shfl_up(v, off, 64);
    if (lane >= off) v += t;
  }
  return v;
}

// ---------- CSR build: phase A — bucket edges by dst>>8 ----------
__global__ __launch_bounds__(1024) void k_bucket(const int* __restrict__ src,
                                                 const int* __restrict__ dst,
                                                 int* __restrict__ bucket_cnt,
                                                 int2* __restrict__ region) {
  __shared__ int bcnt[NBUCK];
  __shared__ int lbase[NBUCK];
  __shared__ int gpos[NBUCK];
  __shared__ int2 stage[4096];
  int tid = threadIdx.x;
  if (tid < NBUCK) bcnt[tid] = 0;
  __syncthreads();
  int e0 = blockIdx.x * 4096;
  int2 rec0, rec1, rec2, rec3;
  int bk0 = -1, bk1 = -1, bk2 = -1, bk3 = -1;
  int rk0 = 0, rk1 = 0, rk2 = 0, rk3 = 0;
#define LOADA(i) { int e = e0 + tid + i * 1024;                                  \
    if (e < N_EDGES) { rec##i.x = src[e]; rec##i.y = dst[e];                     \
      bk##i = rec##i.y >> 8; rk##i = atomicAdd(&bcnt[bk##i], 1); } }
  LOADA(0) LOADA(1) LOADA(2) LOADA(3)
#undef LOADA
  __syncthreads();
  if (tid < 64) {   // exclusive scan of bcnt[196]
    int v0 = (tid * 4 + 0 < NBUCK) ? bcnt[tid * 4 + 0] : 0;
    int v1 = (tid * 4 + 1 < NBUCK) ? bcnt[tid * 4 + 1] : 0;
    int v2 = (tid * 4 + 2 < NBUCK) ? bcnt[tid * 4 + 2] : 0;
    int v3 = (tid * 4 + 3 < NBUCK) ? bcnt[tid * 4 + 3] : 0;
    int s = v0 + v1 + v2 + v3;
    int excl = wave_incl_scan_i(s, tid) - s;
    if (tid * 4 + 0 < NBUCK) lbase[tid * 4 + 0] = excl; excl += v0;
    if (tid * 4 + 1 < NBUCK) lbase[tid * 4 + 1] = excl; excl += v1;
    if (tid * 4 + 2 < NBUCK) lbase[tid * 4 + 2] = excl; excl += v2;
    if (tid * 4 + 3 < NBUCK) lbase[tid * 4 + 3] = excl;
  }
  __syncthreads();
  if (tid < NBUCK && bcnt[tid] > 0) gpos[tid] = atomicAdd(&bucket_cnt[tid], bcnt[tid]);
  if (bk0 >= 0) stage[lbase[bk0] + rk0] = rec0;
  if (bk1 >= 0) stage[lbase[bk1] + rk1] = rec1;
  if (bk2 >= 0) stage[lbase[bk2] + rk2] = rec2;
  if (bk3 >= 0) stage[lbase[bk3] + rk3] = rec3;
  __syncthreads();
  int total = lbase[NBUCK - 1] + bcnt[NBUCK - 1];
  for (int j = tid; j < total; j += 1024) {
    int2 r = stage[j];
    int b = r.y >> 8;
    int k = gpos[b] + (j - lbase[b]);
    if (k < BCAP) region[b * BCAP + k] = r;
  }
}

// ---------- CSR build: scan of bucket counts ----------
__global__ void k_bscan(const int* __restrict__ bucket_cnt,
                        int* __restrict__ bucket_base, int* __restrict__ offs) {
  int lane = threadIdx.x;
  int v0 = (lane * 4 + 0 < NBUCK) ? bucket_cnt[lane * 4 + 0] : 0;
  int v1 = (lane * 4 + 1 < NBUCK) ? bucket_cnt[lane * 4 + 1] : 0;
  int v2 = (lane * 4 + 2 < NBUCK) ? bucket_cnt[lane * 4 + 2] : 0;
  int v3 = (lane * 4 + 3 < NBUCK) ? bucket_cnt[lane * 4 + 3] : 0;
  int s = v0 + v1 + v2 + v3;
  int excl = wave_incl_scan_i(s, lane) - s;
  if (lane * 4 + 0 < NBUCK) bucket_base[lane * 4 + 0] = excl; excl += v0;
  if (lane * 4 + 1 < NBUCK) bucket_base[lane * 4 + 1] = excl; excl += v1;
  if (lane * 4 + 2 < NBUCK) bucket_base[lane * 4 + 2] = excl; excl += v2;
  if (lane * 4 + 3 < NBUCK) bucket_base[lane * 4 + 3] = excl;
  if (lane == 0) offs[N_NODES] = N_EDGES;
}

// ---------- CSR build: phase B — per-bucket fine CSR in LDS ----------
__global__ __launch_bounds__(1024) void k_csr(const int2* __restrict__ region,
                                              const int* __restrict__ bucket_cnt,
                                              const int* __restrict__ bucket_base,
                                              int* __restrict__ offs,
                                              float* __restrict__ dis,
                                              int* __restrict__ esrc) {
  __shared__ int hist[256];
  __shared__ int base[256];
  __shared__ int stage[BCAP];
  int b = blockIdx.x, tid = threadIdx.x;
  int cnt = bucket_cnt[b]; if (cnt > BCAP) cnt = BCAP;
  int bbase = bucket_base[b];
  if (tid < 256) hist[tid] = 0;
  __syncthreads();
  int rec0, rec1, rec2, rec3, rec4;
  int ln0 = -1, ln1 = -1, ln2 = -1, ln3 = -1, ln4 = -1;
  int rk0 = 0, rk1 = 0, rk2 = 0, rk3 = 0, rk4 = 0;
#define LOADB(i) { int j = tid + i * 1024;                                        \
    if (j < cnt) { int2 r = region[b * BCAP + j]; rec##i = r.x;                   \
      ln##i = r.y & 255; rk##i = atomicAdd(&hist[ln##i], 1); } }
  LOADB(0) LOADB(1) LOADB(2) LOADB(3) LOADB(4)
#undef LOADB
  __syncthreads();
  if (tid < 64) {
    int v0 = hist[tid * 4 + 0], v1 = hist[tid * 4 + 1];
    int v2 = hist[tid * 4 + 2], v3 = hist[tid * 4 + 3];
    int s = v0 + v1 + v2 + v3;
    int excl = wave_incl_scan_i(s, tid) - s;
    base[tid * 4 + 0] = excl; excl += v0;
    base[tid * 4 + 1] = excl; excl += v1;
    base[tid * 4 + 2] = excl; excl += v2;
    base[tid * 4 + 3] = excl;
  }
  __syncthreads();
  int node = b * 256 + tid;
  if (tid < 256 && node < N_NODES) {
    offs[node] = bbase + base[tid];
    dis[node] = rsqrtf(1.0f + (float)hist[tid]);
  }
  if (ln0 >= 0) stage[base[ln0] + rk0] = rec0;
  if (ln1 >= 0) stage[base[ln1] + rk1] = rec1;
  if (ln2 >= 0) stage[base[ln2] + rk2] = rec2;
  if (ln3 >= 0) stage[base[ln3] + rk3] = rec3;
  if (ln4 >= 0) stage[base[ln4] + rk4] = rec4;
  __syncthreads();
  for (int j = tid; j < cnt; j += 1024) esrc[bbase + j] = stage[j];
}

// ---------- fp16 helpers ----------
__device__ __forceinline__ void acc8_fp16(float* acc, uint4 u) {
  float2 f;
  f = __half22float2(*(__half2*)&u.x); acc[0] += f.x; acc[1] += f.y;
  f = __half22float2(*(__half2*)&u.y); acc[2] += f.x; acc[3] += f.y;
  f = __half22float2(*(__half2*)&u.z); acc[4] += f.x; acc[5] += f.y;
  f = __half22float2(*(__half2*)&u.w); acc[6] += f.x; acc[7] += f.y;
}

// ---------- layer-1 GEMM via MFMA: T = fp16((X @ W1) * dis), X fp32 K=128 ----------
// W1 staged transposed + swizzled fp16 LDS: byte = col*256 + ((2k) ^ ((col&7)<<4)).
// A frags read fp32 from global, converted in registers.
__global__ __launch_bounds__(256) void k_gemm1_mfma(const float* __restrict__ X,
                                                    const float* __restrict__ W,
                                                    const float* __restrict__ dis,
                                                    __half* __restrict__ T) {
  __shared__ __half wt[128 * 64];
  const int tid = threadIdx.x;
  for (int i = tid; i < 8192; i += 256) {
    int k = i >> 6, col = i & 63;
    int boff = (col << 8) + ((k << 1) ^ ((col & 7) << 4));
    *(__half*)((char*)wt + boff) = __float2half(W[k * 64 + col]);
  }
  __syncthreads();

  const int w = tid >> 6, l = tid & 63;
  const int row0 = blockIdx.x * 64 + w * 16;
  const int arow = row0 + (l & 15);
  const int koff = (l >> 4) << 3;

  half8 a[4];
  #pragma unroll
  for (int s = 0; s < 4; ++s) {
    half8 av = {};
    if (arow < N_NODES) {
      float4 f0 = *(const float4*)&X[arow * 128 + s * 32 + koff];
      float4 f1 = *(const float4*)&X[arow * 128 + s * 32 + koff + 4];
      av[0] = (_Float16)f0.x; av[1] = (_Float16)f0.y;
      av[2] = (_Float16)f0.z; av[3] = (_Float16)f0.w;
      av[4] = (_Float16)f1.x; av[5] = (_Float16)f1.y;
      av[6] = (_Float16)f1.z; av[7] = (_Float16)f1.w;
    }
    a[s] = av;
  }
  f32x4v acc[4] = {{0.f,0.f,0.f,0.f},{0.f,0.f,0.f,0.f},
                   {0.f,0.f,0.f,0.f},{0.f,0.f,0.f,0.f}};
  #pragma unroll
  for (int t = 0; t < 4; ++t) {
    int col = (t << 4) + (l & 15);
    #pragma unroll
    for (int s = 0; s < 4; ++s) {
      int kk = s * 32 + koff;
      half8 b = *(const half8*)((const char*)wt +
                 ((col << 8) + ((kk << 1) ^ ((col & 7) << 4))));
      acc[t] = __builtin_amdgcn_mfma_f32_16x16x32_f16(a[s], b, acc[t], 0, 0, 0);
    }
  }
  #pragma unroll
  for (int r = 0; r < 4; ++r) {
    int row = row0 + ((l >> 4) << 2) + r;
    if (row < N_NODES) {
      float dn = dis[row];
      #pragma unroll
      for (int t = 0; t < 4; ++t)
        T[row * 64 + (t << 4) + (l & 15)] = __float2half(acc[t][r] * dn);
    }
  }
}

// ---------- fused layer: gather (8 lanes/node) + relu -> LDS H -> MFMA GEMM ----------
// Block = 32 nodes. hs swizzled: byte = row*128 + ((2k) ^ ((row&7)<<4)).
__global__ __launch_bounds__(256) void k_gg(const __half* __restrict__ T,
                                            const int* __restrict__ offs,
                                            const int* __restrict__ esrc,
                                            const float* __restrict__ dis,
                                            const float* __restrict__ bias,
                                            const float* __restrict__ W,
                                            __half* __restrict__ Tout) {
  __shared__ __half wt[64 * 64];   // W2^T swizzled fp16
  __shared__ __half hs[32 * 64];   // gathered H rows, swizzled
  const int tid = threadIdx.x;
  for (int i = tid; i < 4096; i += 256) {
    int k = i >> 6, col = i & 63;
    int boff = (col << 7) + ((k << 1) ^ ((col & 7) << 4));
    *(__half*)((char*)wt + boff) = __float2half(W[k * 64 + col]);
  }

  const int n0 = blockIdx.x * 32;
  const int nloc = tid >> 3;
  const int n = n0 + nloc;
  const int l8 = (tid & 7) << 3;
  uint4 hu = make_uint4(0u, 0u, 0u, 0u);
  if (n < N_NODES) {
    int e0 = offs[n], e1 = offs[n + 1];
    float acc[8] = {};
    acc8_fp16(acc, *(const uint4*)&T[n * 64 + l8]);   // self-loop (pre-scaled)
    int e = e0;
    for (; e + 8 <= e1; e += 8) {
      int s0 = esrc[e+0], s1 = esrc[e+1], s2 = esrc[e+2], s3 = esrc[e+3];
      int s4 = esrc[e+4], s5 = esrc[e+5], s6 = esrc[e+6], s7 = esrc[e+7];
      uint4 u0 = *(const uint4*)&T[s0 * 64 + l8];
      uint4 u1 = *(const uint4*)&T[s1 * 64 + l8];
      uint4 u2 = *(const uint4*)&T[s2 * 64 + l8];
      uint4 u3 = *(const uint4*)&T[s3 * 64 + l8];
      uint4 u4 = *(const uint4*)&T[s4 * 64 + l8];
      uint4 u5 = *(const uint4*)&T[s5 * 64 + l8];
      uint4 u6 = *(const uint4*)&T[s6 * 64 + l8];
      uint4 u7 = *(const uint4*)&T[s7 * 64 + l8];
      acc8_fp16(acc, u0); acc8_fp16(acc, u1); acc8_fp16(acc, u2); acc8_fp16(acc, u3);
      acc8_fp16(acc, u4); acc8_fp16(acc, u5); acc8_fp16(acc, u6); acc8_fp16(acc, u7);
    }
    for (; e + 4 <= e1; e += 4) {
      int s0 = esrc[e+0], s1 = esrc[e+1], s2 = esrc[e+2], s3 = esrc[e+3];
      uint4 u0 = *(const uint4*)&T[s0 * 64 + l8];
      uint4 u1 = *(const uint4*)&T[s1 * 64 + l8];
      uint4 u2 = *(const uint4*)&T[s2 * 64 + l8];
      uint4 u3 = *(const uint4*)&T[s3 * 64 + l8];
      acc8_fp16(acc, u0); acc8_fp16(acc, u1); acc8_fp16(acc, u2); acc8_fp16(acc, u3);
    }
    for (; e < e1; ++e) {
      acc8_fp16(acc, *(const uint4*)&T[esrc[e] * 64 + l8]);
    }
    float dn = dis[n];
    float4 b0 = *(const float4*)&bias[l8];
    float4 b1 = *(const float4*)&bias[l8 + 4];
    __half2 h0 = __floats2half2_rn(fmaxf(fmaf(dn, acc[0], b0.x), 0.f),
                                   fmaxf(fmaf(dn, acc[1], b0.y), 0.f));
    __half2 h1 = __floats2half2_rn(fmaxf(fmaf(dn, acc[2], b0.z), 0.f),
                                   fmaxf(fmaf(dn, acc[3], b0.w), 0.f));
    __half2 h2 = __floats2half2_rn(fmaxf(fmaf(dn, acc[4], b1.x), 0.f),
                                   fmaxf(fmaf(dn, acc[5], b1.y), 0.f));
    __half2 h3 = __floats2half2_rn(fmaxf(fmaf(dn, acc[6], b1.z), 0.f),
                                   fmaxf(fmaf(dn, acc[7], b1.w), 0.f));
    hu = make_uint4(*(unsigned*)&h0, *(unsigned*)&h1,
                    *(unsigned*)&h2, *(unsigned*)&h3);
  }
  *(uint4*)((char*)hs + ((nloc << 7) + ((l8 << 1) ^ ((nloc & 7) << 4)))) = hu;
  __syncthreads();

  // MFMA: 4 waves cover 32 rows x 64 cols (wave: rows 16*(w>>1), cols 32*(w&1))
  const int w = tid >> 6, l = tid & 63;
  const int rt = (w >> 1) << 4;
  const int ct0 = (w & 1) << 1;
  const int arowl = rt + (l & 15);
  const int koff = (l >> 4) << 3;
  half8 a0 = *(const half8*)((const char*)hs +
              ((arowl << 7) + ((koff << 1) ^ ((arowl & 7) << 4))));
  half8 a1 = *(const half8*)((const char*)hs +
              ((arowl << 7) + (((koff + 32) << 1) ^ ((arowl & 7) << 4))));
  f32x4v acc2[2] = {{0.f,0.f,0.f,0.f},{0.f,0.f,0.f,0.f}};
  #pragma unroll
  for (int t = 0; t < 2; ++t) {
    int col = ((ct0 + t) << 4) + (l & 15);
    half8 b0 = *(const half8*)((const char*)wt +
                ((col << 7) + ((koff << 1) ^ ((col & 7) << 4))));
    half8 b1 = *(const half8*)((const char*)wt +
                ((col << 7) + (((koff + 32) << 1) ^ ((col & 7) << 4))));
    acc2[t] = __builtin_amdgcn_mfma_f32_16x16x32_f16(a0, b0, acc2[t], 0, 0, 0);
    acc2[t] = __builtin_amdgcn_mfma_f32_16x16x32_f16(a1, b1, acc2[t], 0, 0, 0);
  }
  #pragma unroll
  for (int r = 0; r < 4; ++r) {
    int row = n0 + rt + ((l >> 4) << 2) + r;
    if (row < N_NODES) {
      float dn = dis[row];
      #pragma unroll
      for (int t = 0; t < 2; ++t)
        Tout[row * 64 + ((ct0 + t) << 4) + (l & 15)] = __float2half(acc2[t][r] * dn);
    }
  }
}

// ---------- final: gather + relu + dot(Wl) -> per-node scalar ----------
__global__ __launch_bounds__(256) void k_final(const __half* __restrict__ T,
                                               const int* __restrict__ offs,
                                               const int* __restrict__ esrc,
                                               const float* __restrict__ dis,
                                               const float* __restrict__ bias,
                                               const float* __restrict__ Wl,
                                               float* __restrict__ pern) {
  int tid = threadIdx.x;
  int n = blockIdx.x * 32 + (tid >> 3);
  int l8 = (tid & 7) << 3;
  if (n >= N_NODES) return;
  int e0 = offs[n], e1 = offs[n + 1];
  float acc[8] = {};
  acc8_fp16(acc, *(const uint4*)&T[n * 64 + l8]);
  int e = e0;
  for (; e + 8 <= e1; e += 8) {
    int s0 = esrc[e+0], s1 = esrc[e+1], s2 = esrc[e+2], s3 = esrc[e+3];
    int s4 = esrc[e+4], s5 = esrc[e+5], s6 = esrc[e+6], s7 = esrc[e+7];
    uint4 u0 = *(const uint4*)&T[s0 * 64 + l8];
    uint4 u1 = *(const uint4*)&T[s1 * 64 + l8];
    uint4 u2 = *(const uint4*)&T[s2 * 64 + l8];
    uint4 u3 = *(const uint4*)&T[s3 * 64 + l8];
    uint4 u4 = *(const uint4*)&T[s4 * 64 + l8];
    uint4 u5 = *(const uint4*)&T[s5 * 64 + l8];
    uint4 u6 = *(const uint4*)&T[s6 * 64 + l8];
    uint4 u7 = *(const uint4*)&T[s7 * 64 + l8];
    acc8_fp16(acc, u0); acc8_fp16(acc, u1); acc8_fp16(acc, u2); acc8_fp16(acc, u3);
    acc8_fp16(acc, u4); acc8_fp16(acc, u5); acc8_fp16(acc, u6); acc8_fp16(acc, u7);
  }
  for (; e + 4 <= e1; e += 4) {
    int s0 = esrc[e+0], s1 = esrc[e+1], s2 = esrc[e+2], s3 = esrc[e+3];
    uint4 u0 = *(const uint4*)&T[s0 * 64 + l8];
    uint4 u1 = *(const uint4*)&T[s1 * 64 + l8];
    uint4 u2 = *(const uint4*)&T[s2 * 64 + l8];
    uint4 u3 = *(const uint4*)&T[s3 * 64 + l8];
    acc8_fp16(acc, u0); acc8_fp16(acc, u1); acc8_fp16(acc, u2); acc8_fp16(acc, u3);
  }
  for (; e < e1; ++e) {
    acc8_fp16(acc, *(const uint4*)&T[esrc[e] * 64 + l8]);
  }
  float dn = dis[n];
  float4 b0 = *(const float4*)&bias[l8];
  float4 b1 = *(const float4*)&bias[l8 + 4];
  float4 w0 = *(const float4*)&Wl[l8];
  float4 w1 = *(const float4*)&Wl[l8 + 4];
  float s = fmaxf(fmaf(dn, acc[0], b0.x), 0.f) * w0.x
          + fmaxf(fmaf(dn, acc[1], b0.y), 0.f) * w0.y
          + fmaxf(fmaf(dn, acc[2], b0.z), 0.f) * w0.z
          + fmaxf(fmaf(dn, acc[3], b0.w), 0.f) * w0.w
          + fmaxf(fmaf(dn, acc[4], b1.x), 0.f) * w1.x
          + fmaxf(fmaf(dn, acc[5], b1.y), 0.f) * w1.y
          + fmaxf(fmaf(dn, acc[6], b1.z), 0.f) * w1.z
          + fmaxf(fmaf(dn, acc[7], b1.w), 0.f) * w1.w;
  s += __shfl_xor(s, 1, 64);
  s += __shfl_xor(s, 2, 64);
  s += __shfl_xor(s, 4, 64);
  if ((tid & 7) == 0) pern[n] = s;
}

// ---------- per-graph mean of per-node scalars + bl ----------
__global__ __launch_bounds__(64) void k_pool2(const float* __restrict__ pern,
                                              const int* __restrict__ batch,
                                              const float* __restrict__ bl,
                                              float* __restrict__ out) {
  int g = blockIdx.x;
  int lane = threadIdx.x;
  int lo = 0, hi = N_NODES;
  while (lo < hi) { int mid = (lo + hi) >> 1; if (batch[mid] < g) lo = mid + 1; else hi = mid; }
  int start = lo;
  hi = N_NODES;
  while (lo < hi) { int mid = (lo + hi) >> 1; if (batch[mid] < g + 1) lo = mid + 1; else hi = mid; }
  int end = lo;
  float acc = 0.f;
  for (int nn = start + lane; nn < end; nn += 64) acc += pern[nn];
  #pragma unroll
  for (int off = 32; off; off >>= 1) acc += __shfl_down(acc, off, 64);
  if (lane == 0) {
    float cntf = (float)(end - start);
    out[g] = acc / fmaxf(cntf, 1.0f) + bl[0];
  }
}

extern "C" void kernel_launch(void* const* d_in, const int* in_sizes, int n_in,
                              void* d_out, int out_size, void* d_ws, size_t ws_size,
                              hipStream_t stream) {
  const float* x    = (const float*)d_in[0];
  const float* W1   = (const float*)d_in[1];
  const float* b1   = (const float*)d_in[2];
  const float* W2   = (const float*)d_in[3];
  const float* b2   = (const float*)d_in[4];
  const float* Wl   = (const float*)d_in[5];
  const float* bl   = (const float*)d_in[6];
  const int*   eidx = (const int*)d_in[7];
  const int*   batch= (const int*)d_in[8];
  const int* e_src = eidx;             // edge_index[0]
  const int* e_dst = eidx + N_EDGES;   // edge_index[1]
  float* out = (float*)d_out;

  char* w = (char*)d_ws;
  size_t o = 0;
  auto alloc = [&](size_t bytes) { void* p = w + o; o += (bytes + 255) & ~(size_t)255; return p; };
  float*  dis    = (float*) alloc(N_NODES * 4);
  int*    offs   = (int*)   alloc((N_NODES + 1) * 4);
  int*    esrc   = (int*)   alloc((size_t)N_EDGES * 4);
  int*    bcnt   = (int*)   alloc(NBUCK * 4);
  int*    bbase  = (int*)   alloc(NBUCK * 4);
  int2*   region = (int2*)  alloc((size_t)NBUCK * BCAP * 8);
  __half* bufT   = (__half*)alloc((size_t)N_NODES * HID * 2);
  __half* bufU   = (__half*)alloc((size_t)N_NODES * HID * 2);
  float*  pern   = (float*) alloc(N_NODES * 4);

  const int NBG = (N_NODES + 63) / 64;   // 64-row blocks (layer-1 GEMM)
  const int NGA = (N_NODES + 31) / 32;   // 32-node blocks (fused/gather)

  (void)hipMemsetAsync(bcnt, 0, NBUCK * 4, stream);
  k_bucket<<<(N_EDGES + 4095) / 4096, 1024, 0, stream>>>(e_src, e_dst, bcnt, region);
  k_bscan <<<1, 64, 0, stream>>>(bcnt, bbase, offs);
  k_csr   <<<NBUCK, 1024, 0, stream>>>(region, bcnt, bbase, offs, dis, esrc);

  k_gemm1_mfma<<<NBG, 256, 0, stream>>>(x, W1, dis, bufT);                    // -> T1
  k_gg  <<<NGA, 256, 0, stream>>>(bufT, offs, esrc, dis, b1, W2, bufU);       // T1 -> T2
  k_gg  <<<NGA, 256, 0, stream>>>(bufU, offs, esrc, dis, b2, W2, bufT);       // T2 -> T3
  k_gg  <<<NGA, 256, 0, stream>>>(bufT, offs, esrc, dis, b2, W2, bufU);       // T3 -> T4
  k_gg  <<<NGA, 256, 0, stream>>>(bufU, offs, esrc, dis, b2, W2, bufT);       // T4 -> T5
  k_final<<<NGA, 256, 0, stream>>>(bufT, offs, esrc, dis, b2, Wl, pern);
  k_pool2<<<N_GRAPHS, 64, 0, stream>>>(pern, batch, bl, out);
}